// Round 13
// baseline (228.157 us; speedup 1.0000x reference)
//
#include <hip/hip_runtime.h>
#include <math.h>

#define B_ 2
#define S_ 2048
#define D_ 1024
#define H_ 16
#define HD_ 64
#define LOG2E 1.44269504088896340736f

typedef __bf16 bf16_t;
typedef bf16_t bf16x8 __attribute__((ext_vector_type(8)));
typedef bf16_t bf16x4v __attribute__((ext_vector_type(4)));
typedef float f32x4 __attribute__((ext_vector_type(4)));

#define GLOBAL_LOAD_LDS16(gp, lp)                                              \
    __builtin_amdgcn_global_load_lds(                                          \
        (const __attribute__((address_space(1))) void*)(gp),                   \
        (__attribute__((address_space(3))) void*)(lp), 16, 0, 0)

// Raw hardware exp2: 1 instruction (R10-measured: -10us attn vs ocml exp2f).
static __device__ __forceinline__ float exp2_raw(float x)
{
    float r;
    asm("v_exp_f32 %0, %1" : "=v"(r) : "v"(x));
    return r;
}

// ============================================================================
// fp32 -> bf16 cast, flat grid (unchanged from R10-measured).
// ============================================================================
__global__ __launch_bounds__(256) void cvt_kernel(
    const float* __restrict__ q, const float* __restrict__ k,
    const float* __restrict__ v, const float* __restrict__ wq,
    const float* __restrict__ wk, const float* __restrict__ wv,
    bf16_t* __restrict__ qb, bf16_t* __restrict__ kb, bf16_t* __restrict__ vb,
    bf16_t* __restrict__ wqb, bf16_t* __restrict__ wkb, bf16_t* __restrict__ wvb)
{
    const size_t NT = (size_t)1 << 20;          // vec4 groups per q/k/v tensor
    const size_t NW = (size_t)1 << 18;          // vec4 groups per weight
    size_t g = (size_t)blockIdx.x * 256 + threadIdx.x;

    const float* src;
    bf16_t* dst;
    size_t off;
    if (g < 3 * NT) {
        int t = (int)(g >> 20);
        off = (g & (NT - 1)) * 4;
        src = (t == 0) ? q : (t == 1) ? k : v;
        dst = (t == 0) ? qb : (t == 1) ? kb : vb;
    } else {
        size_t gw = g - 3 * NT;
        if (gw >= 3 * NW) return;
        int t = (int)(gw >> 18);
        off = (gw & (NW - 1)) * 4;
        src = (t == 0) ? wq : (t == 1) ? wk : wv;
        dst = (t == 0) ? wqb : (t == 1) ? wkb : wvb;
    }

    float4 f = *(const float4*)(src + off);
    bf16x4v o;
    o[0] = (bf16_t)f.x; o[1] = (bf16_t)f.y;
    o[2] = (bf16_t)f.z; o[3] = (bf16_t)f.w;
    *(bf16x4v*)(dst + off) = o;
}

// ============================================================================
// Fused projection GEMM — unchanged from R10-measured (m97 2-barrier, bf16).
// ============================================================================
__global__ __launch_bounds__(256) void proj_mfma(
    const bf16_t* __restrict__ X0, const bf16_t* __restrict__ X1,
    const bf16_t* __restrict__ X2, const bf16_t* __restrict__ W0,
    const bf16_t* __restrict__ W1, const bf16_t* __restrict__ W2,
    const float* __restrict__ b0, const float* __restrict__ b1,
    const float* __restrict__ b2, bf16_t* __restrict__ o0,
    bf16_t* __restrict__ o1, bf16_t* __restrict__ o2)
{
    __shared__ __align__(16) bf16_t As[128 * 32];
    __shared__ __align__(16) bf16_t Bs[128 * 32];

    const int z = blockIdx.z;
    const bf16_t* X = (z == 0) ? X0 : (z == 1) ? X1 : X2;
    const bf16_t* W = (z == 0) ? W0 : (z == 1) ? W1 : W2;
    const float* bias = (z == 0) ? b0 : (z == 1) ? b1 : b2;
    bf16_t* out = (z == 0) ? o0 : (z == 1) ? o1 : o2;
    const float oscale = (z == 0) ? (0.125f * LOG2E) : 1.0f;

    const int tid  = threadIdx.x;
    const int w    = tid >> 6;
    const int lane = tid & 63;
    const int L    = lane & 15;
    const int quad = lane >> 4;
    const int wr   = (w >> 1) * 64;
    const int wc   = (w & 1) * 64;
    const int row0 = blockIdx.x * 128;
    const int col0 = blockIdx.y * 128;

    const int lr = lane >> 2;
    const int lc = (lane & 3) * 8;

    f32x4 acc[4][4];
    #pragma unroll
    for (int i = 0; i < 4; ++i)
        #pragma unroll
        for (int j = 0; j < 4; ++j) {
            acc[i][j][0] = 0.f; acc[i][j][1] = 0.f;
            acc[i][j][2] = 0.f; acc[i][j][3] = 0.f;
        }

    for (int k0 = 0; k0 < D_; k0 += 32) {
        __syncthreads();
        #pragma unroll
        for (int i = 0; i < 2; ++i) {
            const int rA = i * 64 + w * 16;
            GLOBAL_LOAD_LDS16(X + (size_t)(row0 + rA + lr) * D_ + k0 + lc,
                              &As[rA * 32]);
            GLOBAL_LOAD_LDS16(W + (size_t)(col0 + rA + lr) * D_ + k0 + lc,
                              &Bs[rA * 32]);
        }
        __syncthreads();

        bf16x8 aF[4], bF[4];
        #pragma unroll
        for (int t = 0; t < 4; ++t) {
            aF[t] = *(const bf16x8*)&As[(wr + t * 16 + L) * 32 + quad * 8];
            bF[t] = *(const bf16x8*)&Bs[(wc + t * 16 + L) * 32 + quad * 8];
        }
        #pragma unroll
        for (int mt = 0; mt < 4; ++mt)
            #pragma unroll
            for (int nt = 0; nt < 4; ++nt)
                acc[mt][nt] = __builtin_amdgcn_mfma_f32_16x16x32_bf16(
                    aF[mt], bF[nt], acc[mt][nt], 0, 0, 0);
    }

    if (z == 2) {
        // ---- direct V^T epilogue: vt[((b*H+h)*HD+hd)*S + s] ----
        #pragma unroll
        for (int nt = 0; nt < 4; ++nt) {
            const int j  = col0 + wc + nt * 16 + L;
            const float bval = bias[j];
            const int h  = j >> 6;
            const int hd = j & 63;
            #pragma unroll
            for (int mt = 0; mt < 4; ++mt) {
                const int n0 = row0 + wr + mt * 16 + quad * 4;
                const int b  = n0 >> 11;
                const int s  = n0 & (S_ - 1);
                bf16x4v p;
                #pragma unroll
                for (int r = 0; r < 4; ++r)
                    p[r] = (bf16_t)(acc[mt][nt][r] + bval);
                *(bf16x4v*)(out + ((size_t)(b * H_ + h) * HD_ + hd) * S_ + s) = p;
            }
        }
    } else {
        #pragma unroll
        for (int nt = 0; nt < 4; ++nt) {
            const int j  = col0 + wc + nt * 16 + L;
            const float bval = bias[j];
            const int h  = j >> 6;
            const int hd = j & 63;
            #pragma unroll
            for (int mt = 0; mt < 4; ++mt)
                #pragma unroll
                for (int r = 0; r < 4; ++r) {
                    const int n = row0 + wr + mt * 16 + quad * 4 + r;
                    const int b = n >> 11;
                    const int s = n & (S_ - 1);
                    out[((((size_t)b * H_ + h) * S_ + s) * HD_) + hd] =
                        (bf16_t)((acc[mt][nt][r] + bval) * oscale);
                }
        }
    }
}

// ============================================================================
// MFMA flash attention — R10-measured core loop (4 waves x 32 q, REVERTED
// from the failed 8-wave R12), with an S-SPLIT by 2 for occupancy:
// grid 512 -> 1024 blocks (4 blocks/CU, was 2), each block does 16 K-tiles
// (half the key range) — total staging volume UNCHANGED (unlike R3's q-split).
// Fixed-bias softmax => partials combine by pure addition: half 0 writes
// unnormalized o to `out`, half 1 to `po`; partial row-sums to `pl`;
// combine_kernel adds + normalizes + applies the q-mask.
// ============================================================================
__global__ __launch_bounds__(256) void attn_kernel(
    const bf16_t* __restrict__ Q, const bf16_t* __restrict__ K,
    const bf16_t* __restrict__ Vt, const int* __restrict__ mask,
    float* __restrict__ out, float* __restrict__ po, float* __restrict__ pl)
{
    __shared__ bf16_t Ks[2][64 * 64];
    __shared__ bf16_t Vs[2][64 * 64];     // [d][key]
    __shared__ bf16_t Pt[4][32 * 64];     // per-wave P, [q(32)][key(64)]

    const int tid  = threadIdx.x;
    const int w    = tid >> 6;
    const int lane = tid & 63;
    const int L    = lane & 15;
    const int quad = lane >> 4;
    const int L7   = L & 7;

    const float VB = -8.0f * LOG2E;       // valid key: exp2(z - 8*log2e)
    const float MB = -1.44269504e30f;     // masked key: exp2 -> 0

    // XCD swizzle: nwg = 16*16*4 = 1024 = 8*128 (bijective).
    const int orig = blockIdx.x + 16 * (blockIdx.y + 16 * blockIdx.z);
    const int work = (orig & 7) * 128 + (orig >> 3);
    const int q0   = (work & 15) * 128;
    const int h    = (work >> 4) & 15;
    const int bhf  = work >> 8;           // 0..3
    const int b    = bhf >> 1;
    const int half = bhf & 1;
    const int bh   = b * H_ + h;

    const bf16_t* kbase = K  + ((size_t)bh * S_ + half * 1024) * HD_;
    const bf16_t* vbase = Vt + (size_t)bh * HD_ * S_ + half * 1024;
    const int*    mrow  = mask + b * S_ + half * 1024;

    // staging: 256 threads cover 64x64 bf16 as rows sr/sr+32, 16B slot c8
    const int sr  = tid >> 3;             // 0..31
    const int c8  = tid & 7;              // slot
    const int sc2 = c8 * 8;
    const int swz = ((c8 ^ (sr & 7)) * 8);
    const int st0 = sr * 64 + swz;
    const int st1 = (sr + 32) * 64 + swz; // (sr+32)&7 == sr&7

    // Q fragments (one-time)
    bf16x8 aQ[2][2];
    #pragma unroll
    for (int qb = 0; qb < 2; ++qb) {
        const bf16_t* qp = Q + ((size_t)bh * S_ + q0 + w * 32 + qb * 16 + L) * HD_;
        aQ[qb][0] = *(const bf16x8*)(qp + quad * 8);
        aQ[qb][1] = *(const bf16x8*)(qp + 32 + quad * 8);
    }

    f32x4 o[2][4];
    #pragma unroll
    for (int qb = 0; qb < 2; ++qb)
        #pragma unroll
        for (int f = 0; f < 4; ++f) {
            o[qb][f][0]=0.f; o[qb][f][1]=0.f; o[qb][f][2]=0.f; o[qb][f][3]=0.f;
        }
    f32x4 ol[2];
    #pragma unroll
    for (int qb = 0; qb < 2; ++qb) {
        ol[qb][0]=0.f; ol[qb][1]=0.f; ol[qb][2]=0.f; ol[qb][3]=0.f;
    }

    bf16x8 ones;
    #pragma unroll
    for (int i = 0; i < 8; ++i) ones[i] = (bf16_t)1.0f;

    // ---- prologue: tile0 -> buf0; tile1 -> regs ----
    bf16x8 kr0, kr1, vr0, vr1;
    f32x4  bias_c[4], bias_n[4];
    kr0 = *(const bf16x8*)(kbase + (size_t)sr * HD_ + sc2);
    kr1 = *(const bf16x8*)(kbase + (size_t)(sr + 32) * HD_ + sc2);
    vr0 = *(const bf16x8*)(vbase + (size_t)sr * S_ + sc2);
    vr1 = *(const bf16x8*)(vbase + (size_t)(sr + 32) * S_ + sc2);
    #pragma unroll
    for (int f = 0; f < 4; ++f) {
        int4 mi = *(const int4*)(mrow + f * 16 + quad * 4);
        bias_c[f][0] = mi.x ? VB : MB;
        bias_c[f][1] = mi.y ? VB : MB;
        bias_c[f][2] = mi.z ? VB : MB;
        bias_c[f][3] = mi.w ? VB : MB;
    }

    *(bf16x8*)&Ks[0][st0] = kr0;
    *(bf16x8*)&Ks[0][st1] = kr1;
    *(bf16x8*)&Vs[0][st0] = vr0;
    *(bf16x8*)&Vs[0][st1] = vr1;

    kr0 = *(const bf16x8*)(kbase + (size_t)(64 + sr) * HD_ + sc2);
    kr1 = *(const bf16x8*)(kbase + (size_t)(64 + sr + 32) * HD_ + sc2);
    vr0 = *(const bf16x8*)(vbase + (size_t)sr * S_ + 64 + sc2);
    vr1 = *(const bf16x8*)(vbase + (size_t)(sr + 32) * S_ + 64 + sc2);
    #pragma unroll
    for (int f = 0; f < 4; ++f) {
        int4 mi = *(const int4*)(mrow + 64 + f * 16 + quad * 4);
        bias_n[f][0] = mi.x ? VB : MB;
        bias_n[f][1] = mi.y ? VB : MB;
        bias_n[f][2] = mi.z ? VB : MB;
        bias_n[f][3] = mi.w ? VB : MB;
    }

    __syncthreads();

    for (int t = 0; t < 16; ++t) {
        const int cur = t & 1;
        bf16_t* ks  = &Ks[cur][0];
        bf16_t* vs  = &Vs[cur][0];

        // ---- write tile t+1 regs -> other buffer; issue tile t+2 loads ----
        if (t < 15) {
            bf16_t* ksn = &Ks[cur ^ 1][0];
            bf16_t* vsn = &Vs[cur ^ 1][0];
            *(bf16x8*)&ksn[st0] = kr0;
            *(bf16x8*)&ksn[st1] = kr1;
            *(bf16x8*)&vsn[st0] = vr0;
            *(bf16x8*)&vsn[st1] = vr1;
        }
        if (t < 14) {
            const int kn = (t + 2) * 64;
            kr0 = *(const bf16x8*)(kbase + (size_t)(kn + sr) * HD_ + sc2);
            kr1 = *(const bf16x8*)(kbase + (size_t)(kn + sr + 32) * HD_ + sc2);
            vr0 = *(const bf16x8*)(vbase + (size_t)sr * S_ + kn + sc2);
            vr1 = *(const bf16x8*)(vbase + (size_t)(sr + 32) * S_ + kn + sc2);
        }

        // ---- K fragments (swizzled reads) ----
        bf16x8 aK[4][2];
        #pragma unroll
        for (int f = 0; f < 4; ++f) {
            const int row = (f * 16 + L) * 64;
            aK[f][0] = *(const bf16x8*)&ks[row + ((quad ^ L7) * 8)];
            aK[f][1] = *(const bf16x8*)&ks[row + (((4 | quad) ^ L7) * 8)];
        }

        // ---- S^T = K.Q^T, p = exp2(s'), packed swizzled P staging ----
        bf16_t* pw = &Pt[w][0];
        #pragma unroll
        for (int qb = 0; qb < 2; ++qb) {
            const int prow = (qb * 16 + L) * 64;
            #pragma unroll
            for (int f = 0; f < 4; ++f) {
                f32x4 z = bias_c[f];   // rows = keys f*16+quad*4+r
                z = __builtin_amdgcn_mfma_f32_16x16x32_bf16(aK[f][0], aQ[qb][0], z, 0, 0, 0);
                z = __builtin_amdgcn_mfma_f32_16x16x32_bf16(aK[f][1], aQ[qb][1], z, 0, 0, 0);
                bf16x4v p4;
                p4[0] = (bf16_t)exp2_raw(z[0]);
                p4[1] = (bf16_t)exp2_raw(z[1]);
                p4[2] = (bf16_t)exp2_raw(z[2]);
                p4[3] = (bf16_t)exp2_raw(z[3]);
                *(bf16x4v*)&pw[prow + (((f * 2 + (quad >> 1)) ^ L7) * 8) + (quad & 1) * 4] = p4;
            }
        }

        // ---- rotate bias regs; build tile t+2 bias from mask ----
        #pragma unroll
        for (int f = 0; f < 4; ++f) bias_c[f] = bias_n[f];
        if (t < 14) {
            const int kn = (t + 2) * 64;
            #pragma unroll
            for (int f = 0; f < 4; ++f) {
                int4 mi = *(const int4*)(mrow + kn + f * 16 + quad * 4);
                bias_n[f][0] = mi.x ? VB : MB;
                bias_n[f][1] = mi.y ? VB : MB;
                bias_n[f][2] = mi.z ? VB : MB;
                bias_n[f][3] = mi.w ? VB : MB;
            }
        }

        // ---- P fragments (swizzled) + ones-column row-sum ----
        bf16x8 aP[2][2];
        #pragma unroll
        for (int qb = 0; qb < 2; ++qb) {
            const int prow = (qb * 16 + L) * 64;
            aP[qb][0] = *(const bf16x8*)&pw[prow + ((quad ^ L7) * 8)];
            aP[qb][1] = *(const bf16x8*)&pw[prow + (((4 | quad) ^ L7) * 8)];
            ol[qb] = __builtin_amdgcn_mfma_f32_16x16x32_bf16(aP[qb][0], ones, ol[qb], 0, 0, 0);
            ol[qb] = __builtin_amdgcn_mfma_f32_16x16x32_bf16(aP[qb][1], ones, ol[qb], 0, 0, 0);
        }

        // ---- PV: bV read once per f, shared across qb ----
        #pragma unroll
        for (int f = 0; f < 4; ++f) {
            const int row = (f * 16 + L) * 64;
            bf16x8 bV0 = *(const bf16x8*)&vs[row + ((quad ^ L7) * 8)];
            bf16x8 bV1 = *(const bf16x8*)&vs[row + (((4 | quad) ^ L7) * 8)];
            #pragma unroll
            for (int qb = 0; qb < 2; ++qb) {
                o[qb][f] = __builtin_amdgcn_mfma_f32_16x16x32_bf16(aP[qb][0], bV0, o[qb][f], 0, 0, 0);
                o[qb][f] = __builtin_amdgcn_mfma_f32_16x16x32_bf16(aP[qb][1], bV1, o[qb][f], 0, 0, 0);
            }
        }

        __syncthreads();   // one barrier/tile
    }

    // ---- epilogue: RAW partial write (normalization in combine_kernel) ----
    float* dst = half ? po : out;
    #pragma unroll
    for (int qb = 0; qb < 2; ++qb) {
        float* obase = dst + ((size_t)b * S_ + q0 + w * 32 + qb * 16 + quad * 4) * D_ + h * HD_;
        #pragma unroll
        for (int f = 0; f < 4; ++f)
            #pragma unroll
            for (int r = 0; r < 4; ++r)
                obase[r * D_ + f * 16 + L] = o[qb][f][r];

        if (L == 0) {
            float* plh = pl + (size_t)half * (B_ * H_ * S_)
                            + (size_t)bh * S_ + q0 + w * 32 + qb * 16 + quad * 4;
            #pragma unroll
            for (int r = 0; r < 4; ++r)
                plh[r] = ol[qb][r];
        }
    }
}

// ============================================================================
// Combine: out = (out_half0 + po_half1) / (l0 + l1), zeroed for masked q.
// ============================================================================
__global__ __launch_bounds__(256) void combine_kernel(
    const float* __restrict__ po, const float* __restrict__ pl,
    const int* __restrict__ mask, float* __restrict__ out)
{
    size_t e = ((size_t)blockIdx.x * 256 + threadIdx.x) * 4;
    const int d = (int)(e & (D_ - 1));
    const int s = (int)((e >> 10) & (S_ - 1));
    const int b = (int)(e >> 21);
    const int h = d >> 6;

    const size_t li = (size_t)(b * H_ + h) * S_ + s;
    float l = pl[li] + pl[(size_t)B_ * H_ * S_ + li];
    float inv = (mask[b * S_ + s] && l > 0.f) ? (1.0f / l) : 0.0f;

    float4 a = *(const float4*)(out + e);
    float4 c = *(const float4*)(po + e);
    float4 r;
    r.x = (a.x + c.x) * inv;
    r.y = (a.y + c.y) * inv;
    r.z = (a.z + c.z) * inv;
    r.w = (a.w + c.w) * inv;
    *(float4*)(out + e) = r;
}

// ============================================================================
extern "C" void kernel_launch(void* const* d_in, const int* in_sizes, int n_in,
                              void* d_out, int out_size, void* d_ws, size_t ws_size,
                              hipStream_t stream)
{
    const float* q    = (const float*)d_in[0];
    const float* k    = (const float*)d_in[1];
    const float* v    = (const float*)d_in[2];
    const int*   mask = (const int*)d_in[3];
    const float* Wq   = (const float*)d_in[4];
    const float* bq   = (const float*)d_in[5];
    const float* Wk   = (const float*)d_in[6];
    const float* bk   = (const float*)d_in[7];
    const float* Wv   = (const float*)d_in[8];
    const float* bv   = (const float*)d_in[9];
    float* out = (float*)d_out;

    const size_t PE = (size_t)B_ * S_ * D_;           // 4,194,304 per tensor
    const size_t WE = (size_t)D_ * D_;                // 1,048,576 per weight

    bf16_t* qb  = (bf16_t*)d_ws;
    bf16_t* kb  = qb + PE;
    bf16_t* vb  = kb + PE;
    bf16_t* wqb = vb + PE;
    bf16_t* wkb = wqb + WE;
    bf16_t* wvb = wkb + WE;
    bf16_t* mq  = wvb + WE;
    bf16_t* mk  = mq + PE;
    bf16_t* vt  = mk + PE;                // V^T written directly by proj z==2

    // attn partials reuse qb/kb/vb (dead after proj; stream-ordered):
    float* po = (float*)d_ws;             // PE f32 = 16MB over qb+kb
    float* pl = (float*)d_ws + PE;        // 2*B*H*S f32 = 512KB, inside vb

    // cvt: 3*2^20 + 3*2^18 vec4 groups = 3,932,160 -> 15,360 blocks
    const size_t ngroups = 3 * (PE / 4) + 3 * (WE / 4);
    dim3 cgrid((ngroups + 255) / 256);
    cvt_kernel<<<cgrid, 256, 0, stream>>>(q, k, v, Wq, Wk, Wv,
                                          qb, kb, vb, wqb, wkb, wvb);

    dim3 pgrid(4096 / 128, 1024 / 128, 3);
    proj_mfma<<<pgrid, 256, 0, stream>>>(qb, kb, vb, wqb, wkb, wvb,
                                         bq, bk, bv, mq, mk, vt);

    dim3 agrid(S_ / 128, H_, B_ * 2);     // x2: S-split halves
    attn_kernel<<<agrid, 256, 0, stream>>>(mq, mk, vt, mask, out, po, pl);

    dim3 ggrid((unsigned)(PE / 4 / 256));
    combine_kernel<<<ggrid, 256, 0, stream>>>(po, pl, mask, out);
}

// Round 14
// 210.589 us; speedup vs baseline: 1.0834x; 1.0834x over previous
//
#include <hip/hip_runtime.h>
#include <math.h>

#define B_ 2
#define S_ 2048
#define D_ 1024
#define H_ 16
#define HD_ 64
#define LOG2E 1.44269504088896340736f

typedef __bf16 bf16_t;
typedef bf16_t bf16x8 __attribute__((ext_vector_type(8)));
typedef bf16_t bf16x4v __attribute__((ext_vector_type(4)));
typedef float f32x4 __attribute__((ext_vector_type(4)));

#define GLOBAL_LOAD_LDS16(gp, lp)                                              \
    __builtin_amdgcn_global_load_lds(                                          \
        (const __attribute__((address_space(1))) void*)(gp),                   \
        (__attribute__((address_space(3))) void*)(lp), 16, 0, 0)

// Raw hardware exp2: 1 instruction (R10-measured: -10us attn vs ocml exp2f).
static __device__ __forceinline__ float exp2_raw(float x)
{
    float r;
    asm("v_exp_f32 %0, %1" : "=v"(r) : "v"(x));
    return r;
}

// ============================================================================
// fp32 -> bf16 cast, flat grid (unchanged from R10-measured).
// ============================================================================
__global__ __launch_bounds__(256) void cvt_kernel(
    const float* __restrict__ q, const float* __restrict__ k,
    const float* __restrict__ v, const float* __restrict__ wq,
    const float* __restrict__ wk, const float* __restrict__ wv,
    bf16_t* __restrict__ qb, bf16_t* __restrict__ kb, bf16_t* __restrict__ vb,
    bf16_t* __restrict__ wqb, bf16_t* __restrict__ wkb, bf16_t* __restrict__ wvb)
{
    const size_t NT = (size_t)1 << 20;          // vec4 groups per q/k/v tensor
    const size_t NW = (size_t)1 << 18;          // vec4 groups per weight
    size_t g = (size_t)blockIdx.x * 256 + threadIdx.x;

    const float* src;
    bf16_t* dst;
    size_t off;
    if (g < 3 * NT) {
        int t = (int)(g >> 20);
        off = (g & (NT - 1)) * 4;
        src = (t == 0) ? q : (t == 1) ? k : v;
        dst = (t == 0) ? qb : (t == 1) ? kb : vb;
    } else {
        size_t gw = g - 3 * NT;
        if (gw >= 3 * NW) return;
        int t = (int)(gw >> 18);
        off = (gw & (NW - 1)) * 4;
        src = (t == 0) ? wq : (t == 1) ? wk : wv;
        dst = (t == 0) ? wqb : (t == 1) ? wkb : wvb;
    }

    float4 f = *(const float4*)(src + off);
    bf16x4v o;
    o[0] = (bf16_t)f.x; o[1] = (bf16_t)f.y;
    o[2] = (bf16_t)f.z; o[3] = (bf16_t)f.w;
    *(bf16x4v*)(dst + off) = o;
}

// ============================================================================
// Fused projection GEMM — unchanged from R10-measured (m97 2-barrier, bf16).
// ============================================================================
__global__ __launch_bounds__(256) void proj_mfma(
    const bf16_t* __restrict__ X0, const bf16_t* __restrict__ X1,
    const bf16_t* __restrict__ X2, const bf16_t* __restrict__ W0,
    const bf16_t* __restrict__ W1, const bf16_t* __restrict__ W2,
    const float* __restrict__ b0, const float* __restrict__ b1,
    const float* __restrict__ b2, bf16_t* __restrict__ o0,
    bf16_t* __restrict__ o1, bf16_t* __restrict__ o2)
{
    __shared__ __align__(16) bf16_t As[128 * 32];
    __shared__ __align__(16) bf16_t Bs[128 * 32];

    const int z = blockIdx.z;
    const bf16_t* X = (z == 0) ? X0 : (z == 1) ? X1 : X2;
    const bf16_t* W = (z == 0) ? W0 : (z == 1) ? W1 : W2;
    const float* bias = (z == 0) ? b0 : (z == 1) ? b1 : b2;
    bf16_t* out = (z == 0) ? o0 : (z == 1) ? o1 : o2;
    const float oscale = (z == 0) ? (0.125f * LOG2E) : 1.0f;

    const int tid  = threadIdx.x;
    const int w    = tid >> 6;
    const int lane = tid & 63;
    const int L    = lane & 15;
    const int quad = lane >> 4;
    const int wr   = (w >> 1) * 64;
    const int wc   = (w & 1) * 64;
    const int row0 = blockIdx.x * 128;
    const int col0 = blockIdx.y * 128;

    const int lr = lane >> 2;
    const int lc = (lane & 3) * 8;

    f32x4 acc[4][4];
    #pragma unroll
    for (int i = 0; i < 4; ++i)
        #pragma unroll
        for (int j = 0; j < 4; ++j) {
            acc[i][j][0] = 0.f; acc[i][j][1] = 0.f;
            acc[i][j][2] = 0.f; acc[i][j][3] = 0.f;
        }

    for (int k0 = 0; k0 < D_; k0 += 32) {
        __syncthreads();
        #pragma unroll
        for (int i = 0; i < 2; ++i) {
            const int rA = i * 64 + w * 16;
            GLOBAL_LOAD_LDS16(X + (size_t)(row0 + rA + lr) * D_ + k0 + lc,
                              &As[rA * 32]);
            GLOBAL_LOAD_LDS16(W + (size_t)(col0 + rA + lr) * D_ + k0 + lc,
                              &Bs[rA * 32]);
        }
        __syncthreads();

        bf16x8 aF[4], bF[4];
        #pragma unroll
        for (int t = 0; t < 4; ++t) {
            aF[t] = *(const bf16x8*)&As[(wr + t * 16 + L) * 32 + quad * 8];
            bF[t] = *(const bf16x8*)&Bs[(wc + t * 16 + L) * 32 + quad * 8];
        }
        #pragma unroll
        for (int mt = 0; mt < 4; ++mt)
            #pragma unroll
            for (int nt = 0; nt < 4; ++nt)
                acc[mt][nt] = __builtin_amdgcn_mfma_f32_16x16x32_bf16(
                    aF[mt], bF[nt], acc[mt][nt], 0, 0, 0);
    }

    if (z == 2) {
        // ---- direct V^T epilogue: vt[((b*H+h)*HD+hd)*S + s] ----
        #pragma unroll
        for (int nt = 0; nt < 4; ++nt) {
            const int j  = col0 + wc + nt * 16 + L;
            const float bval = bias[j];
            const int h  = j >> 6;
            const int hd = j & 63;
            #pragma unroll
            for (int mt = 0; mt < 4; ++mt) {
                const int n0 = row0 + wr + mt * 16 + quad * 4;
                const int b  = n0 >> 11;
                const int s  = n0 & (S_ - 1);
                bf16x4v p;
                #pragma unroll
                for (int r = 0; r < 4; ++r)
                    p[r] = (bf16_t)(acc[mt][nt][r] + bval);
                *(bf16x4v*)(out + ((size_t)(b * H_ + h) * HD_ + hd) * S_ + s) = p;
            }
        }
    } else {
        #pragma unroll
        for (int nt = 0; nt < 4; ++nt) {
            const int j  = col0 + wc + nt * 16 + L;
            const float bval = bias[j];
            const int h  = j >> 6;
            const int hd = j & 63;
            #pragma unroll
            for (int mt = 0; mt < 4; ++mt)
                #pragma unroll
                for (int r = 0; r < 4; ++r) {
                    const int n = row0 + wr + mt * 16 + quad * 4 + r;
                    const int b = n >> 11;
                    const int s = n & (S_ - 1);
                    out[((((size_t)b * H_ + h) * S_ + s) * HD_) + hd] =
                        (bf16_t)((acc[mt][nt][r] + bval) * oscale);
                }
        }
    }
}

// ============================================================================
// MFMA flash attention — R10-measured core (4 waves x 32 q, grid 512, S-split
// REVERTED: R13 falsified occupancy as the constraint), with DEFERRED PV:
// PV(t-1) executes from carried registers (aPp, vFp) at the TOP of iter t,
// independent of iter t's ds_read -> QK -> exp2 chain, so the scheduler can
// overlap PV MFMAs with the exp2/VALU phase (T15-analog; +48 VGPR, costless:
// occupancy is grid-limited at 2 waves/SIMD which the 129-256 tier allows).
// Hazards: aP(t) registerized before Pt reuse at t+1; Vs[cur] live through
// iter t (only buf^1 written); ol stays at iter t so l is complete.
// ============================================================================
__global__ __launch_bounds__(256) void attn_kernel(
    const bf16_t* __restrict__ Q, const bf16_t* __restrict__ K,
    const bf16_t* __restrict__ Vt, const int* __restrict__ mask,
    float* __restrict__ out)
{
    __shared__ bf16_t Ks[2][64 * 64];
    __shared__ bf16_t Vs[2][64 * 64];     // [d][key]
    __shared__ bf16_t Pt[4][32 * 64];     // per-wave P, [q(32)][key(64)]

    const int tid  = threadIdx.x;
    const int w    = tid >> 6;
    const int lane = tid & 63;
    const int L    = lane & 15;
    const int quad = lane >> 4;
    const int L7   = L & 7;

    const float VB = -8.0f * LOG2E;       // valid key: exp2(z - 8*log2e)
    const float MB = -1.44269504e30f;     // masked key: exp2 -> 0

    // XCD swizzle: nwg = 16*16*2 = 512 = 8*64 (bijective).
    const int orig = blockIdx.x + 16 * (blockIdx.y + 16 * blockIdx.z);
    const int work = (orig & 7) * 64 + (orig >> 3);
    const int q0   = (work & 15) * 128;
    const int h    = (work >> 4) & 15;
    const int b    = work >> 8;
    const int bh   = b * H_ + h;

    const bf16_t* kbase = K  + (size_t)bh * S_ * HD_;
    const bf16_t* vbase = Vt + (size_t)bh * HD_ * S_;
    const int*    mrow  = mask + b * S_;

    // staging: 256 threads cover 64x64 bf16 as rows sr/sr+32, 16B slot c8
    const int sr  = tid >> 3;             // 0..31
    const int c8  = tid & 7;              // slot
    const int sc2 = c8 * 8;
    const int swz = ((c8 ^ (sr & 7)) * 8);
    const int st0 = sr * 64 + swz;
    const int st1 = (sr + 32) * 64 + swz; // (sr+32)&7 == sr&7

    // Q fragments (one-time)
    bf16x8 aQ[2][2];
    #pragma unroll
    for (int qb = 0; qb < 2; ++qb) {
        const bf16_t* qp = Q + ((size_t)bh * S_ + q0 + w * 32 + qb * 16 + L) * HD_;
        aQ[qb][0] = *(const bf16x8*)(qp + quad * 8);
        aQ[qb][1] = *(const bf16x8*)(qp + 32 + quad * 8);
    }

    f32x4 o[2][4];
    #pragma unroll
    for (int qb = 0; qb < 2; ++qb)
        #pragma unroll
        for (int f = 0; f < 4; ++f) {
            o[qb][f][0]=0.f; o[qb][f][1]=0.f; o[qb][f][2]=0.f; o[qb][f][3]=0.f;
        }
    f32x4 ol[2];
    #pragma unroll
    for (int qb = 0; qb < 2; ++qb) {
        ol[qb][0]=0.f; ol[qb][1]=0.f; ol[qb][2]=0.f; ol[qb][3]=0.f;
    }

    bf16x8 ones;
    #pragma unroll
    for (int i = 0; i < 8; ++i) ones[i] = (bf16_t)1.0f;

    // ---- prologue: tile0 -> buf0; tile1 -> regs ----
    bf16x8 kr0, kr1, vr0, vr1;
    f32x4  bias_c[4], bias_n[4];
    kr0 = *(const bf16x8*)(kbase + (size_t)sr * HD_ + sc2);
    kr1 = *(const bf16x8*)(kbase + (size_t)(sr + 32) * HD_ + sc2);
    vr0 = *(const bf16x8*)(vbase + (size_t)sr * S_ + sc2);
    vr1 = *(const bf16x8*)(vbase + (size_t)(sr + 32) * S_ + sc2);
    #pragma unroll
    for (int f = 0; f < 4; ++f) {
        int4 mi = *(const int4*)(mrow + f * 16 + quad * 4);
        bias_c[f][0] = mi.x ? VB : MB;
        bias_c[f][1] = mi.y ? VB : MB;
        bias_c[f][2] = mi.z ? VB : MB;
        bias_c[f][3] = mi.w ? VB : MB;
    }

    *(bf16x8*)&Ks[0][st0] = kr0;
    *(bf16x8*)&Ks[0][st1] = kr1;
    *(bf16x8*)&Vs[0][st0] = vr0;
    *(bf16x8*)&Vs[0][st1] = vr1;

    kr0 = *(const bf16x8*)(kbase + (size_t)(64 + sr) * HD_ + sc2);
    kr1 = *(const bf16x8*)(kbase + (size_t)(64 + sr + 32) * HD_ + sc2);
    vr0 = *(const bf16x8*)(vbase + (size_t)sr * S_ + 64 + sc2);
    vr1 = *(const bf16x8*)(vbase + (size_t)(sr + 32) * S_ + 64 + sc2);
    #pragma unroll
    for (int f = 0; f < 4; ++f) {
        int4 mi = *(const int4*)(mrow + 64 + f * 16 + quad * 4);
        bias_n[f][0] = mi.x ? VB : MB;
        bias_n[f][1] = mi.y ? VB : MB;
        bias_n[f][2] = mi.z ? VB : MB;
        bias_n[f][3] = mi.w ? VB : MB;
    }

    __syncthreads();

    // carried registers for deferred PV (written at iter t, used at t+1)
    bf16x8 aPp[2][2];   // P fragments of previous tile
    bf16x8 vFp[4][2];   // V fragments of previous tile

    for (int t = 0; t < 32; ++t) {
        const int cur = t & 1;
        bf16_t* ks  = &Ks[cur][0];
        bf16_t* vs  = &Vs[cur][0];

        // ---- write tile t+1 regs -> other buffer; issue tile t+2 loads ----
        if (t < 31) {
            bf16_t* ksn = &Ks[cur ^ 1][0];
            bf16_t* vsn = &Vs[cur ^ 1][0];
            *(bf16x8*)&ksn[st0] = kr0;
            *(bf16x8*)&ksn[st1] = kr1;
            *(bf16x8*)&vsn[st0] = vr0;
            *(bf16x8*)&vsn[st1] = vr1;
        }
        if (t < 30) {
            const int kn = (t + 2) * 64;
            kr0 = *(const bf16x8*)(kbase + (size_t)(kn + sr) * HD_ + sc2);
            kr1 = *(const bf16x8*)(kbase + (size_t)(kn + sr + 32) * HD_ + sc2);
            vr0 = *(const bf16x8*)(vbase + (size_t)sr * S_ + kn + sc2);
            vr1 = *(const bf16x8*)(vbase + (size_t)(sr + 32) * S_ + kn + sc2);
        }

        // ---- DEFERRED PV(t-1): pure-register MFMAs, independent of this
        // iteration's ds_read/QK/exp2 chain -> scheduler overlap ----
        if (t > 0) {
            #pragma unroll
            for (int f = 0; f < 4; ++f)
                #pragma unroll
                for (int qb = 0; qb < 2; ++qb) {
                    o[qb][f] = __builtin_amdgcn_mfma_f32_16x16x32_bf16(aPp[qb][0], vFp[f][0], o[qb][f], 0, 0, 0);
                    o[qb][f] = __builtin_amdgcn_mfma_f32_16x16x32_bf16(aPp[qb][1], vFp[f][1], o[qb][f], 0, 0, 0);
                }
        }

        // ---- K fragments (swizzled reads) ----
        bf16x8 aK[4][2];
        #pragma unroll
        for (int f = 0; f < 4; ++f) {
            const int row = (f * 16 + L) * 64;
            aK[f][0] = *(const bf16x8*)&ks[row + ((quad ^ L7) * 8)];
            aK[f][1] = *(const bf16x8*)&ks[row + (((4 | quad) ^ L7) * 8)];
        }

        // ---- S^T = K.Q^T, p = exp2(s'), packed swizzled P staging ----
        bf16_t* pw = &Pt[w][0];
        #pragma unroll
        for (int qb = 0; qb < 2; ++qb) {
            const int prow = (qb * 16 + L) * 64;
            #pragma unroll
            for (int f = 0; f < 4; ++f) {
                f32x4 z = bias_c[f];   // rows = keys f*16+quad*4+r
                z = __builtin_amdgcn_mfma_f32_16x16x32_bf16(aK[f][0], aQ[qb][0], z, 0, 0, 0);
                z = __builtin_amdgcn_mfma_f32_16x16x32_bf16(aK[f][1], aQ[qb][1], z, 0, 0, 0);
                bf16x4v p4;
                p4[0] = (bf16_t)exp2_raw(z[0]);
                p4[1] = (bf16_t)exp2_raw(z[1]);
                p4[2] = (bf16_t)exp2_raw(z[2]);
                p4[3] = (bf16_t)exp2_raw(z[3]);
                *(bf16x4v*)&pw[prow + (((f * 2 + (quad >> 1)) ^ L7) * 8) + (quad & 1) * 4] = p4;
            }
        }

        // ---- rotate bias regs; build tile t+2 bias from mask ----
        #pragma unroll
        for (int f = 0; f < 4; ++f) bias_c[f] = bias_n[f];
        if (t < 30) {
            const int kn = (t + 2) * 64;
            #pragma unroll
            for (int f = 0; f < 4; ++f) {
                int4 mi = *(const int4*)(mrow + kn + f * 16 + quad * 4);
                bias_n[f][0] = mi.x ? VB : MB;
                bias_n[f][1] = mi.y ? VB : MB;
                bias_n[f][2] = mi.z ? VB : MB;
                bias_n[f][3] = mi.w ? VB : MB;
            }
        }

        // ---- P fragments (swizzled) + ones-column row-sum (tile t now) ----
        #pragma unroll
        for (int qb = 0; qb < 2; ++qb) {
            const int prow = (qb * 16 + L) * 64;
            aPp[qb][0] = *(const bf16x8*)&pw[prow + ((quad ^ L7) * 8)];
            aPp[qb][1] = *(const bf16x8*)&pw[prow + (((4 | quad) ^ L7) * 8)];
            ol[qb] = __builtin_amdgcn_mfma_f32_16x16x32_bf16(aPp[qb][0], ones, ol[qb], 0, 0, 0);
            ol[qb] = __builtin_amdgcn_mfma_f32_16x16x32_bf16(aPp[qb][1], ones, ol[qb], 0, 0, 0);
        }

        // ---- V fragments for tile t -> carried regs (used at t+1) ----
        #pragma unroll
        for (int f = 0; f < 4; ++f) {
            const int row = (f * 16 + L) * 64;
            vFp[f][0] = *(const bf16x8*)&vs[row + ((quad ^ L7) * 8)];
            vFp[f][1] = *(const bf16x8*)&vs[row + (((4 | quad) ^ L7) * 8)];
        }

        __syncthreads();   // one barrier/tile
    }

    // ---- peeled PV for the last tile ----
    #pragma unroll
    for (int f = 0; f < 4; ++f)
        #pragma unroll
        for (int qb = 0; qb < 2; ++qb) {
            o[qb][f] = __builtin_amdgcn_mfma_f32_16x16x32_bf16(aPp[qb][0], vFp[f][0], o[qb][f], 0, 0, 0);
            o[qb][f] = __builtin_amdgcn_mfma_f32_16x16x32_bf16(aPp[qb][1], vFp[f][1], o[qb][f], 0, 0, 0);
        }

    // ---- epilogue: per-lane l aligned with o rows ----
    #pragma unroll
    for (int qb = 0; qb < 2; ++qb) {
        const int4 m4 = *(const int4*)&mrow[q0 + w * 32 + qb * 16 + quad * 4];
        float inv[4];
        inv[0] = (m4.x && ol[qb][0] > 0.f) ? (1.0f / ol[qb][0]) : 0.0f;
        inv[1] = (m4.y && ol[qb][1] > 0.f) ? (1.0f / ol[qb][1]) : 0.0f;
        inv[2] = (m4.z && ol[qb][2] > 0.f) ? (1.0f / ol[qb][2]) : 0.0f;
        inv[3] = (m4.w && ol[qb][3] > 0.f) ? (1.0f / ol[qb][3]) : 0.0f;

        float* obase = out + ((size_t)b * S_ + q0 + w * 32 + qb * 16 + quad * 4) * D_ + h * HD_;
        #pragma unroll
        for (int f = 0; f < 4; ++f)
            #pragma unroll
            for (int r = 0; r < 4; ++r)
                obase[r * D_ + f * 16 + L] = o[qb][f][r] * inv[r];
    }
}

// ============================================================================
extern "C" void kernel_launch(void* const* d_in, const int* in_sizes, int n_in,
                              void* d_out, int out_size, void* d_ws, size_t ws_size,
                              hipStream_t stream)
{
    const float* q    = (const float*)d_in[0];
    const float* k    = (const float*)d_in[1];
    const float* v    = (const float*)d_in[2];
    const int*   mask = (const int*)d_in[3];
    const float* Wq   = (const float*)d_in[4];
    const float* bq   = (const float*)d_in[5];
    const float* Wk   = (const float*)d_in[6];
    const float* bk   = (const float*)d_in[7];
    const float* Wv   = (const float*)d_in[8];
    const float* bv   = (const float*)d_in[9];
    float* out = (float*)d_out;

    const size_t PE = (size_t)B_ * S_ * D_;           // 4,194,304 per tensor
    const size_t WE = (size_t)D_ * D_;                // 1,048,576 per weight

    bf16_t* qb  = (bf16_t*)d_ws;
    bf16_t* kb  = qb + PE;
    bf16_t* vb  = kb + PE;
    bf16_t* wqb = vb + PE;
    bf16_t* wkb = wqb + WE;
    bf16_t* wvb = wkb + WE;
    bf16_t* mq  = wvb + WE;
    bf16_t* mk  = mq + PE;
    bf16_t* vt  = mk + PE;                // V^T written directly by proj z==2

    // cvt: 3*2^20 + 3*2^18 vec4 groups = 3,932,160 -> 15,360 blocks
    const size_t ngroups = 3 * (PE / 4) + 3 * (WE / 4);
    dim3 cgrid((ngroups + 255) / 256);
    cvt_kernel<<<cgrid, 256, 0, stream>>>(q, k, v, Wq, Wk, Wv,
                                          qb, kb, vb, wqb, wkb, wvb);

    dim3 pgrid(4096 / 128, 1024 / 128, 3);
    proj_mfma<<<pgrid, 256, 0, stream>>>(qb, kb, vb, wqb, wkb, wvb,
                                         bq, bk, bv, mq, mk, vt);

    dim3 agrid(S_ / 128, H_, B_);
    attn_kernel<<<agrid, 256, 0, stream>>>(mq, mk, vt, mask, out);
}